// Round 4
// baseline (43.678 us; speedup 1.0000x reference)
//
#include <hip/hip_runtime.h>

#define GROUPS 196

typedef float v2f __attribute__((ext_vector_type(2)));

__device__ __forceinline__ float dppL(float v) {   // value at px-1, 0 at px==0
    return __int_as_float(__builtin_amdgcn_update_dpp(
        0, __float_as_int(v), 0x111, 0xF, 0xF, true));
}
__device__ __forceinline__ float dppR(float v) {   // value at px+1, 0 at px==15
    return __int_as_float(__builtin_amdgcn_update_dpp(
        0, __float_as_int(v), 0x101, 0xF, 0xF, true));
}
__device__ __forceinline__ v2f dppL2(v2f v) { v2f r; r.x = dppL(v.x); r.y = dppL(v.y); return r; }
__device__ __forceinline__ v2f dppR2(v2f v) { v2f r; r.x = dppR(v.x); r.y = dppR(v.y); return r; }

__device__ __forceinline__ v2f sp(float s) { v2f r; r.x = s; r.y = s; return r; }

__device__ __forceinline__ v2f fma2(v2f a, v2f b, v2f c) {
    return __builtin_elementwise_fma(a, b, c);
}

// quick_gelu: v / (1 + exp2(-1.702*log2e * v))
__device__ __forceinline__ v2f qgelu2(v2f v) {
    v2f kv = v * (-2.45547217f);
    v2f e; e.x = exp2f(kv.x); e.y = exp2f(kv.y);
    v2f den = e + 1.0f;
    v2f r; r.x = __builtin_amdgcn_rcpf(den.x); r.y = __builtin_amdgcn_rcpf(den.y);
    return v * r;
}

__global__ __launch_bounds__(128) void convpass_fused(
    const float* __restrict__ x,
    const float* __restrict__ conv_w,
    const float* __restrict__ conv_b,
    const float* __restrict__ centers,
    const float* __restrict__ widths,
    const float* __restrict__ down_w,
    const float* __restrict__ down_b,
    float* __restrict__ out)
{
    const int g = blockIdx.x;       // group == token-1 (uniform -> s_loads)
    const int b = blockIdx.y;       // batch
    const int tid = threadIdx.x;    // 128 threads, 2 pixels each: rows py and py+8
    const int px = tid & 15;
    const int py = tid >> 4;                 // 0..7
    const int ipA = (py + 1) * 16 + px;      // interior index, pixel A (row py)
    const int ipB = ipA + 128;               // pixel B (row py+8)

    __shared__ float s_in[3][288];           // 3 channel planes, 18 rows x 16 px
    __shared__ v2f   s_rs01[3][288];         // row-sums, bins {0,1} per hist plane
    __shared__ v2f   s_rs23[3][288];         // row-sums, bins {2,3}

    // ---- zero halo rows 0 and 17 ----
    if (tid < 32) {
        const int pix = (tid < 16) ? tid : (272 + (tid - 16));
        s_in[0][pix] = 0.f; s_in[1][pix] = 0.f; s_in[2][pix] = 0.f;
        const v2f z = sp(0.f);
        s_rs01[0][pix] = z; s_rs01[1][pix] = z; s_rs01[2][pix] = z;
        s_rs23[0][pix] = z; s_rs23[1][pix] = z; s_rs23[2][pix] = z;
    }

    // ---- stage input (coalesced; A/B writes fuse to ds_write2) ----
    const float* xin = x + ((size_t)b * 197 + (size_t)(g + 1)) * 768;
    #pragma unroll
    for (int c = 0; c < 3; ++c) {
        s_in[c][ipA] = xin[c * 256 + tid];
        s_in[c][ipB] = xin[c * 256 + 128 + tid];
    }
    __syncthreads();

    // ---- grouped 3x3 conv: vertical via LDS (ds_read2), horizontal via DPP ----
    const float* cw = conv_w + g * 81;
    v2f acc0 = sp(conv_b[g * 3 + 0]);
    v2f acc1 = sp(conv_b[g * 3 + 1]);
    v2f acc2 = sp(conv_b[g * 3 + 2]);

    #pragma unroll
    for (int ky = 0; ky < 3; ++ky) {
        #pragma unroll
        for (int ic = 0; ic < 3; ++ic) {
            const int idx = (py + ky) * 16 + px;   // A taps rows py..py+2 (halo)
            v2f c; c.x = s_in[ic][idx]; c.y = s_in[ic][idx + 128];
            const v2f l = dppL2(c);
            const v2f r = dppR2(c);
            const float* wp = cw + ic * 9 + ky * 3;   // + oc*27 + kx
            acc0 = fma2(l, sp(wp[0]),      fma2(c, sp(wp[1]),      fma2(r, sp(wp[2]),      acc0)));
            acc1 = fma2(l, sp(wp[27 + 0]), fma2(c, sp(wp[27 + 1]), fma2(r, sp(wp[27 + 2]), acc1)));
            acc2 = fma2(l, sp(wp[54 + 0]), fma2(c, sp(wp[54 + 1]), fma2(r, sp(wp[54 + 2]), acc2)));
        }
    }

    // ---- quick_gelu + 4-bin soft histogram + horizontal 3-sum ----
    const float* cen = centers + g * 12;
    const float* wid = widths  + g * 12;
    v2f rs[12];
    {
        v2f yv[3] = { qgelu2(acc0), qgelu2(acc1), qgelu2(acc2) };
        #pragma unroll
        for (int oc = 0; oc < 3; ++oc) {
            v2f t[4];
            v2f ssum = sp(1e-5f);
            #pragma unroll
            for (int k = 0; k < 4; ++k) {
                v2f a = yv[oc] + sp(cen[oc * 4 + k]);
                a.x = fabsf(a.x); a.y = fabsf(a.y);
                v2f tv = fma2(sp(wid[oc * 4 + k]), a, sp(1.0f));
                tv.x = fmaxf(tv.x, 0.f); tv.y = fmaxf(tv.y, 0.f);
                t[k] = tv;
                ssum += tv;
            }
            v2f inv; inv.x = __builtin_amdgcn_rcpf(ssum.x);
                     inv.y = __builtin_amdgcn_rcpf(ssum.y);
            #pragma unroll
            for (int k = 0; k < 4; ++k) {
                const v2f h = t[k] * inv;
                rs[oc * 4 + k] = h + dppL2(h) + dppR2(h);
            }
        }
    }

    // ---- store row-sums (A/B pairs fuse to ds_write2_b64) ----
    #pragma unroll
    for (int oc = 0; oc < 3; ++oc) {
        v2f a01; a01.x = rs[oc * 4 + 0].x; a01.y = rs[oc * 4 + 1].x;
        v2f a23; a23.x = rs[oc * 4 + 2].x; a23.y = rs[oc * 4 + 3].x;
        v2f b01; b01.x = rs[oc * 4 + 0].y; b01.y = rs[oc * 4 + 1].y;
        v2f b23; b23.x = rs[oc * 4 + 2].y; b23.y = rs[oc * 4 + 3].y;
        s_rs01[oc][ipA] = a01; s_rs23[oc][ipA] = a23;
        s_rs01[oc][ipB] = b01; s_rs23[oc][ipB] = b23;
    }
    __syncthreads();

    // ---- vertical 3-sum + exclude-pad scale + quick_gelu + 12->3 proj ----
    const float vx = (float)(1 + (px > 0) + (px < 15));
    const float vyA = (py == 0) ? 2.f : 3.f;   // A rows 0..7: only top edge
    const float vyB = (py == 7) ? 2.f : 3.f;   // B rows 8..15: only bottom edge
    v2f rc; rc.x = __builtin_amdgcn_rcpf(vx * vyA);
            rc.y = __builtin_amdgcn_rcpf(vx * vyB);

    const float* dwp = down_w + g * 36;
    v2f o0 = sp(down_b[g * 3 + 0]);
    v2f o1 = sp(down_b[g * 3 + 1]);
    v2f o2 = sp(down_b[g * 3 + 2]);

    #pragma unroll
    for (int oc = 0; oc < 3; ++oc) {
        const v2f uA01 = s_rs01[oc][ipA - 16], dA01 = s_rs01[oc][ipA + 16];
        const v2f uB01 = s_rs01[oc][ipB - 16], dB01 = s_rs01[oc][ipB + 16];
        const v2f uA23 = s_rs23[oc][ipA - 16], dA23 = s_rs23[oc][ipA + 16];
        const v2f uB23 = s_rs23[oc][ipB - 16], dB23 = s_rs23[oc][ipB + 16];

        v2f s0, s1, s2, s3;
        s0.x = rs[oc * 4 + 0].x + uA01.x + dA01.x;  s0.y = rs[oc * 4 + 0].y + uB01.x + dB01.x;
        s1.x = rs[oc * 4 + 1].x + uA01.y + dA01.y;  s1.y = rs[oc * 4 + 1].y + uB01.y + dB01.y;
        s2.x = rs[oc * 4 + 2].x + uA23.x + dA23.x;  s2.y = rs[oc * 4 + 2].y + uB23.x + dB23.x;
        s3.x = rs[oc * 4 + 3].x + uA23.y + dA23.y;  s3.y = rs[oc * 4 + 3].y + uB23.y + dB23.y;

        const v2f p0 = qgelu2(s0 * rc);
        const v2f p1 = qgelu2(s1 * rc);
        const v2f p2 = qgelu2(s2 * rc);
        const v2f p3 = qgelu2(s3 * rc);

        const int i = oc * 4;
        o0 = fma2(p0, sp(dwp[i]),          fma2(p1, sp(dwp[i + 1]),          fma2(p2, sp(dwp[i + 2]),          fma2(p3, sp(dwp[i + 3]),          o0))));
        o1 = fma2(p0, sp(dwp[12 + i]),     fma2(p1, sp(dwp[12 + i + 1]),     fma2(p2, sp(dwp[12 + i + 2]),     fma2(p3, sp(dwp[12 + i + 3]),     o1))));
        o2 = fma2(p0, sp(dwp[24 + i]),     fma2(p1, sp(dwp[24 + i + 1]),     fma2(p2, sp(dwp[24 + i + 2]),     fma2(p3, sp(dwp[24 + i + 3]),     o2))));
    }

    float* outp = out + ((size_t)b * 197 + (size_t)(g + 1)) * 768;
    outp[tid]           = o0.x;  outp[128 + tid] = o0.y;
    outp[256 + tid]     = o1.x;  outp[384 + tid] = o1.y;
    outp[512 + tid]     = o2.x;  outp[640 + tid] = o2.y;

    // ---- CLS pass-through folded into g==0 blocks ----
    if (g == 0) {
        const float* xc = x + (size_t)b * 197 * 768;
        float* op = out + (size_t)b * 197 * 768;
        #pragma unroll
        for (int k = 0; k < 6; ++k)
            op[k * 128 + tid] = xc[k * 128 + tid];
    }
}

extern "C" void kernel_launch(void* const* d_in, const int* in_sizes, int n_in,
                              void* d_out, int out_size, void* d_ws, size_t ws_size,
                              hipStream_t stream) {
    const float* x       = (const float*)d_in[0];
    const float* conv_w  = (const float*)d_in[1];
    const float* conv_b  = (const float*)d_in[2];
    const float* centers = (const float*)d_in[3];
    const float* widths  = (const float*)d_in[4];
    const float* down_w  = (const float*)d_in[5];
    const float* down_b  = (const float*)d_in[6];
    float* out = (float*)d_out;

    const int B = in_sizes[0] / (197 * 768);

    dim3 grid(GROUPS, B);
    convpass_fused<<<grid, 128, 0, stream>>>(x, conv_w, conv_b, centers, widths,
                                             down_w, down_b, out);
}